// Round 14
// baseline (722.515 us; speedup 1.0000x reference)
//
#include <hip/hip_runtime.h>
#include <stdint.h>

// Problem constants (fixed by reference)
#define BB   4
#define SS   2048
#define DD   1024
#define EE   64
#define CAP  64
#define NTOK (BB*SS)                       // 8192 tokens
#define OUT1_ELEMS (BB*SS*EE*CAP)          // 33,554,432 per output tensor

// ============================================================================
// Round 14: OPTIMIZATION of the passing R13 pipeline (676 us baseline).
// Numerics preserved BIT-EXACTLY (R13 passed at absmax 2.4e-4):
//   - SSE-4-lane einsum: chains s0..s3, k ascending, fp32 mul-then-add,
//     horizontal (s0+s2)+(s1+s3)
//   - noise*2^-6 exact scale + rn add; order-indep max; npyv rational exp;
//     pairwise-8 denominator; rn division
//   - top_k: exact rank on fp32 gate bits, ties -> lower token index
// Perf changes (counter-driven):
//   1. rank: exhaustive O(S^2) scan (214 us, VALU-bound) -> 2-level histogram
//      radix-select + exact rank of ~64-80 candidates only (~25x less work).
//   2. gates: 4 tokens/wave share each W column load (W L2 traffic 2GB->512MB);
//      X via float4 loads (values unchanged).
//   3. writer: compact pick/gval tables (d_ws, 128 KB, L2-hot) + perfectly
//      coalesced float4 streaming stores (no header readback from output).
// ============================================================================

// ---- numpy npyv fp32 exp replica (verbatim from passing R13) --------------
__device__ __forceinline__ float np_expf_npyv(float x) {
    float q = rintf(__fmul_rn(x, 1.442695040888963407e0f));
    float r = __fmaf_rn(q, -6.93145752e-1f, x);
    r = __fmaf_rn(q, -1.42860677e-6f, r);
    float num = 5.082762527590693718096e-04f;
    num = __fmaf_rn(num, r, 6.757896990527504603057e-03f);
    num = __fmaf_rn(num, r, 5.114512081637298353406e-02f);
    num = __fmaf_rn(num, r, 2.473615434895520810817e-01f);
    num = __fmaf_rn(num, r, 7.257664613233124478488e-01f);
    num = __fmaf_rn(num, r, 9.999999999980870924916e-01f);
    float den = 2.159509375685829852307e-02f;
    den = __fmaf_rn(den, r, -2.742335390411667452936e-01f);
    den = __fmaf_rn(den, r, 1.0f);
    float p = __fdiv_rn(num, den);
    return __fmul_rn(p, __int_as_float(((int)q + 127) << 23));
}

// ---------------------------------------------------------------------------
// Kernel 1: gates. 4 waves/block, 4 tokens/wave (16/block), lane = expert.
// Each W column value W[k][lane] is loaded ONCE per wave and feeds 4 tokens'
// chains -> W L2 traffic 512 MB (was 2 GB). Per-dot FP sequence identical to
// R13: s_j chains over k===j (mod 4) ascending, mul-then-add, no FMA.
// ---------------------------------------------------------------------------
__global__ __launch_bounds__(256) void gates_kernel(
        const float* __restrict__ X,       // [NTOK, DD]
        const float* __restrict__ W,       // [DD, EE]
        const float* __restrict__ Nz,      // [NTOK, EE]
        float* __restrict__ G)             // [NTOK, EE] (combine region head)
{
    const int lane = threadIdx.x & 63;     // expert index
    const int wave = threadIdx.x >> 6;
    const int tok0 = blockIdx.x * 16 + wave * 4;

    const float4* X4 = (const float4*)X;
    float s0[4] = {0,0,0,0}, s1[4] = {0,0,0,0};
    float s2[4] = {0,0,0,0}, s3[4] = {0,0,0,0};

    for (int k = 0; k < DD; k += 4) {
        const float w0 = W[(size_t)(k + 0) * EE + lane];
        const float w1 = W[(size_t)(k + 1) * EE + lane];
        const float w2 = W[(size_t)(k + 2) * EE + lane];
        const float w3 = W[(size_t)(k + 3) * EE + lane];
        #pragma unroll
        for (int t = 0; t < 4; ++t) {
            const float4 xv = X4[(size_t)(tok0 + t) * (DD / 4) + (k >> 2)];
            s0[t] = __fadd_rn(s0[t], __fmul_rn(xv.x, w0));
            s1[t] = __fadd_rn(s1[t], __fmul_rn(xv.y, w1));
            s2[t] = __fadd_rn(s2[t], __fmul_rn(xv.z, w2));
            s3[t] = __fadd_rn(s3[t], __fmul_rn(xv.w, w3));
        }
    }

    __shared__ float sl[4][4][64];
    __shared__ float sp[4][4][64];
    #pragma unroll
    for (int t = 0; t < 4; ++t) {
        float acc = __fadd_rn(__fadd_rn(s0[t], s2[t]), __fadd_rn(s1[t], s3[t]));
        float nz = Nz[(size_t)(tok0 + t) * EE + lane];
        sl[wave][t][lane] = __fadd_rn(acc, __fmul_rn(nz, 0.015625f));
    }
    __syncthreads();

    float pv[4];
    #pragma unroll
    for (int t = 0; t < 4; ++t) {
        float m = sl[wave][t][0];          // order-independent max
        for (int i = 1; i < 64; ++i) m = fmaxf(m, sl[wave][t][i]);
        pv[t] = np_expf_npyv(__fsub_rn(sl[wave][t][lane], m));
        sp[wave][t][lane] = pv[t];
    }
    __syncthreads();

    #pragma unroll
    for (int t = 0; t < 4; ++t) {
        // np pairwise_sum n=64: 8 accumulators stride-8, then tree combine
        const float* a = sp[wave][t];
        float r0 = a[0], r1 = a[1], r2 = a[2], r3 = a[3];
        float r4 = a[4], r5 = a[5], r6 = a[6], r7 = a[7];
        for (int i = 8; i < 64; i += 8) {
            r0 = __fadd_rn(r0, a[i + 0]);
            r1 = __fadd_rn(r1, a[i + 1]);
            r2 = __fadd_rn(r2, a[i + 2]);
            r3 = __fadd_rn(r3, a[i + 3]);
            r4 = __fadd_rn(r4, a[i + 4]);
            r5 = __fadd_rn(r5, a[i + 5]);
            r6 = __fadd_rn(r6, a[i + 6]);
            r7 = __fadd_rn(r7, a[i + 7]);
        }
        float Z = __fadd_rn(__fadd_rn(__fadd_rn(r0, r1), __fadd_rn(r2, r3)),
                            __fadd_rn(__fadd_rn(r4, r5), __fadd_rn(r6, r7)));
        G[(size_t)(tok0 + t) * EE + lane] = __fdiv_rn(pv[t], Z);
    }
}

// ---------------------------------------------------------------------------
// Kernel 2: top-64 per (b,e) via 2-level histogram radix-select, then exact
// rank of candidates only. Keys = fp32 gate bits (positive: uint order ==
// float order). Candidate set = {top bits > B1} U {== B1 and sub bits >= S1}
// is a PROVEN superset of the top-64 (higher bit-fields dominate value
// order). Exact rank formula identical to passing R13 (ties -> lower index),
// so results are bit-identical. Emits compact pick/gval tables.
// ---------------------------------------------------------------------------
__global__ __launch_bounds__(512) void rank_kernel(
        const float* __restrict__ G,       // [NTOK, EE]
        int*   __restrict__ pick,          // [BB*EE, CAP]
        float* __restrict__ gval)          // [BB*EE, CAP]
{
    const int tid = threadIdx.x;           // 0..511
    const int be  = blockIdx.x;            // 0..255
    const int b   = be >> 6;
    const int e   = be & 63;

    __shared__ unsigned K[SS];             // 8 KB keys
    __shared__ unsigned hist[4096];        // 16 KB histogram (reused)
    __shared__ int      cand[SS];          // 8 KB candidate tokens
    __shared__ int      rkacc[SS];         // 8 KB partial-rank accum
    __shared__ int      sel[4];            // B1, S1, CHI, ncand

    unsigned mine[4];
    #pragma unroll
    for (int j = 0; j < 4; ++j) {
        const int s = tid + 512 * j;       // covers 0..2047 exactly
        unsigned bits = __float_as_uint(G[((size_t)(b * SS + s)) * EE + e]);
        K[s] = bits;
        mine[j] = bits;
    }
    for (int i = tid; i < 4096; i += 512) hist[i] = 0;
    __syncthreads();

    // Pass 1: coarse histogram on bits [31:20]
    #pragma unroll
    for (int j = 0; j < 4; ++j) atomicAdd(&hist[mine[j] >> 20], 1u);
    __syncthreads();

    if (tid == 0) {
        int acc = 0, bi = 4095;
        for (; bi > 0; --bi) {
            int c = (int)hist[bi];
            if (acc + c >= CAP) break;
            acc += c;
        }
        sel[0] = bi;                       // B1: bin holding the 64th largest
        sel[2] = acc;                      // CHI: #keys strictly above bin B1
    }
    __syncthreads();
    const int B1 = sel[0], CHI = sel[2];

    // Pass 2: refine within B1 on bits [19:8]
    for (int i = tid; i < 4096; i += 512) hist[i] = 0;
    __syncthreads();
    #pragma unroll
    for (int j = 0; j < 4; ++j)
        if ((int)(mine[j] >> 20) == B1)
            atomicAdd(&hist[(mine[j] >> 8) & 0xFFFu], 1u);
    __syncthreads();
    if (tid == 0) {
        const int need = CAP - CHI;        // in [1, 64]
        int acc = 0, si = 4095;
        for (; si > 0; --si) {
            int c = (int)hist[si];
            if (acc + c >= need) break;
            acc += c;
        }
        sel[1] = si;                       // S1
        sel[3] = 0;                        // candidate counter
    }
    __syncthreads();
    const int S1 = sel[1];

    // Compact candidates (superset of top-64; typically ~64-80)
    #pragma unroll
    for (int j = 0; j < 4; ++j) {
        const int top = (int)(mine[j] >> 20);
        const int sub = (int)((mine[j] >> 8) & 0xFFFu);
        if (top > B1 || (top == B1 && sub >= S1)) {
            int idx = atomicAdd(&sel[3], 1);
            cand[idx] = tid + 512 * j;
        }
    }
    __syncthreads();
    const int ncand = sel[3];
    for (int c = tid; c < ncand; c += 512) rkacc[c] = 0;
    __syncthreads();

    // Exact rank of candidates: 4 threads/candidate, 512-key strips each.
    const int quarter = tid & 3;
    for (int cid = tid >> 2; cid < ncand; cid += 128) {
        const int sc = cand[cid];
        const unsigned kc = K[sc];
        int part = 0;
        const int i0 = quarter * 512;
        for (int i = i0; i < i0 + 512; ++i) {
            const unsigned ki = K[i];
            part += (int)(ki > kc) + (int)((ki == kc) && (i < sc));
        }
        atomicAdd(&rkacc[cid], part);
    }
    __syncthreads();

    for (int cid = tid; cid < ncand; cid += 512) {
        const int r = rkacc[cid];
        if (r < CAP) {
            const int sc = cand[cid];
            pick[be * CAP + r] = sc;
            gval[be * CAP + r] = __uint_as_float(K[sc]);
        }
    }
}

// ---------------------------------------------------------------------------
// Kernel 3: streaming writer. Thread g covers 4 consecutive capacity slots of
// one (b,s,e) row for BOTH tensors: mask = (pick==s), combine = mask*gate.
// Consecutive threads -> consecutive float4: perfectly coalesced 1 KiB/wave
// stores per tensor. pick/gval tables (128 KB) are L2-hot broadcast reads.
// ---------------------------------------------------------------------------
__global__ __launch_bounds__(256) void writer_kernel(
        const int4*   __restrict__ pick4,  // [BB*EE, CAP/4]
        const float4* __restrict__ gval4,  // [BB*EE, CAP/4]
        float4* __restrict__ out)          // [2 * OUT1_ELEMS/4]
{
    const unsigned g = blockIdx.x * 256u + threadIdx.x;  // < 8,388,608
    const int c4 = g & 15;
    const int e  = (g >> 4) & 63;
    const unsigned bs = g >> 10;           // 0..8191
    const int s  = bs & 2047;
    const int b  = bs >> 11;
    const int be = b * EE + e;

    const int4   pk = pick4[be * (CAP / 4) + c4];
    const float4 gv = gval4[be * (CAP / 4) + c4];

    float4 msk, cmb;
    msk.x = (pk.x == s) ? 1.0f : 0.0f;  cmb.x = (pk.x == s) ? gv.x : 0.0f;
    msk.y = (pk.y == s) ? 1.0f : 0.0f;  cmb.y = (pk.y == s) ? gv.y : 0.0f;
    msk.z = (pk.z == s) ? 1.0f : 0.0f;  cmb.z = (pk.z == s) ? gv.z : 0.0f;
    msk.w = (pk.w == s) ? 1.0f : 0.0f;  cmb.w = (pk.w == s) ? gv.w : 0.0f;

    out[g] = msk;                          // dispatch_mask
    out[g + OUT1_ELEMS / 4] = cmb;         // combine_weights
}

// ---------------------------------------------------------------------------
extern "C" void kernel_launch(void* const* d_in, const int* in_sizes, int n_in,
                              void* d_out, int out_size, void* d_ws, size_t ws_size,
                              hipStream_t stream) {
    const float* X     = (const float*)d_in[0];   // [4,2048,1024] fp32
    const float* W     = (const float*)d_in[1];   // [1024,64]     fp32
    const float* noise = (const float*)d_in[2];   // [4,2048,64]   fp32
    float* outb = (float*)d_out;   // mask ++ combine, fp32

    // G table (2 MiB) at the combine head: written by gates, consumed by
    // rank, overwritten by writer (kernel-order serialization on stream).
    float* G = outb + (size_t)OUT1_ELEMS;
    // Compact tables in d_ws (128 KiB; R1 precedent proves ws writable).
    int*   pick = (int*)d_ws;
    float* gval = (float*)((char*)d_ws + (size_t)BB * EE * CAP * sizeof(int));

    gates_kernel<<<NTOK / 16, 256, 0, stream>>>(X, W, noise, G);
    rank_kernel<<<BB * EE, 512, 0, stream>>>(G, pick, gval);
    writer_kernel<<<OUT1_ELEMS / 4 / 256, 256, 0, stream>>>(
        (const int4*)pick, (const float4*)gval, (float4*)outb);
}

// Round 15
// 400.658 us; speedup vs baseline: 1.8033x; 1.8033x over previous
//
#include <hip/hip_runtime.h>
#include <stdint.h>

// Problem constants (fixed by reference)
#define BB   4
#define SS   2048
#define DD   1024
#define EE   64
#define CAP  64
#define NTOK (BB*SS)                       // 8192 tokens
#define OUT1_ELEMS (BB*SS*EE*CAP)          // 33,554,432 per output tensor

// ============================================================================
// Round 15: fix the R14 rank regression (361 us, VALUBusy 2.7%, 1.6M LDS
// bank conflicts from same-bin histogram atomics + single-thread 4096-bin
// scans). New selection: per-(b,e) BITWISE BINARY SEARCH of the 64th-largest
// key (30 iterations, shfl-reduce + ping-pong LDS combine, 1 barrier/iter,
// ZERO atomics in the search), then exact rank of the ~64 candidates with
// R13's proven tie formula -> output bit-identical to the passing R13/R14.
// Gates and writer kernels: verbatim from R14 (both passed bit-exact).
// ============================================================================

// ---- numpy npyv fp32 exp replica (verbatim from passing R13) --------------
__device__ __forceinline__ float np_expf_npyv(float x) {
    float q = rintf(__fmul_rn(x, 1.442695040888963407e0f));
    float r = __fmaf_rn(q, -6.93145752e-1f, x);
    r = __fmaf_rn(q, -1.42860677e-6f, r);
    float num = 5.082762527590693718096e-04f;
    num = __fmaf_rn(num, r, 6.757896990527504603057e-03f);
    num = __fmaf_rn(num, r, 5.114512081637298353406e-02f);
    num = __fmaf_rn(num, r, 2.473615434895520810817e-01f);
    num = __fmaf_rn(num, r, 7.257664613233124478488e-01f);
    num = __fmaf_rn(num, r, 9.999999999980870924916e-01f);
    float den = 2.159509375685829852307e-02f;
    den = __fmaf_rn(den, r, -2.742335390411667452936e-01f);
    den = __fmaf_rn(den, r, 1.0f);
    float p = __fdiv_rn(num, den);
    return __fmul_rn(p, __int_as_float(((int)q + 127) << 23));
}

// ---------------------------------------------------------------------------
// Kernel 1: gates (verbatim R14). 4 waves/block, 4 tokens/wave, lane=expert.
// W column loads shared across 4 tokens; per-dot FP sequence identical to
// R13: SSE 4-lane chains, k ascending, mul-then-add, (s0+s2)+(s1+s3).
// ---------------------------------------------------------------------------
__global__ __launch_bounds__(256) void gates_kernel(
        const float* __restrict__ X,       // [NTOK, DD]
        const float* __restrict__ W,       // [DD, EE]
        const float* __restrict__ Nz,      // [NTOK, EE]
        float* __restrict__ G)             // [NTOK, EE]
{
    const int lane = threadIdx.x & 63;
    const int wave = threadIdx.x >> 6;
    const int tok0 = blockIdx.x * 16 + wave * 4;

    const float4* X4 = (const float4*)X;
    float s0[4] = {0,0,0,0}, s1[4] = {0,0,0,0};
    float s2[4] = {0,0,0,0}, s3[4] = {0,0,0,0};

    for (int k = 0; k < DD; k += 4) {
        const float w0 = W[(size_t)(k + 0) * EE + lane];
        const float w1 = W[(size_t)(k + 1) * EE + lane];
        const float w2 = W[(size_t)(k + 2) * EE + lane];
        const float w3 = W[(size_t)(k + 3) * EE + lane];
        #pragma unroll
        for (int t = 0; t < 4; ++t) {
            const float4 xv = X4[(size_t)(tok0 + t) * (DD / 4) + (k >> 2)];
            s0[t] = __fadd_rn(s0[t], __fmul_rn(xv.x, w0));
            s1[t] = __fadd_rn(s1[t], __fmul_rn(xv.y, w1));
            s2[t] = __fadd_rn(s2[t], __fmul_rn(xv.z, w2));
            s3[t] = __fadd_rn(s3[t], __fmul_rn(xv.w, w3));
        }
    }

    __shared__ float sl[4][4][64];
    __shared__ float sp[4][4][64];
    #pragma unroll
    for (int t = 0; t < 4; ++t) {
        float acc = __fadd_rn(__fadd_rn(s0[t], s2[t]), __fadd_rn(s1[t], s3[t]));
        float nz = Nz[(size_t)(tok0 + t) * EE + lane];
        sl[wave][t][lane] = __fadd_rn(acc, __fmul_rn(nz, 0.015625f));
    }
    __syncthreads();

    float pv[4];
    #pragma unroll
    for (int t = 0; t < 4; ++t) {
        float m = sl[wave][t][0];
        for (int i = 1; i < 64; ++i) m = fmaxf(m, sl[wave][t][i]);
        pv[t] = np_expf_npyv(__fsub_rn(sl[wave][t][lane], m));
        sp[wave][t][lane] = pv[t];
    }
    __syncthreads();

    #pragma unroll
    for (int t = 0; t < 4; ++t) {
        const float* a = sp[wave][t];
        float r0 = a[0], r1 = a[1], r2 = a[2], r3 = a[3];
        float r4 = a[4], r5 = a[5], r6 = a[6], r7 = a[7];
        for (int i = 8; i < 64; i += 8) {
            r0 = __fadd_rn(r0, a[i + 0]);
            r1 = __fadd_rn(r1, a[i + 1]);
            r2 = __fadd_rn(r2, a[i + 2]);
            r3 = __fadd_rn(r3, a[i + 3]);
            r4 = __fadd_rn(r4, a[i + 4]);
            r5 = __fadd_rn(r5, a[i + 5]);
            r6 = __fadd_rn(r6, a[i + 6]);
            r7 = __fadd_rn(r7, a[i + 7]);
        }
        float Z = __fadd_rn(__fadd_rn(__fadd_rn(r0, r1), __fadd_rn(r2, r3)),
                            __fadd_rn(__fadd_rn(r4, r5), __fadd_rn(r6, r7)));
        G[(size_t)(tok0 + t) * EE + lane] = __fdiv_rn(pv[t], Z);
    }
}

// ---------------------------------------------------------------------------
// Kernel 2: top-64 per (b,e) via bitwise binary-search threshold + exact
// candidate rank. Keys = fp32 gate bits (positive: uint order == float
// order; gates < 1.0 -> bits 31,30 are 0 -> search bits 29..0).
// Search invariant: T = max value with count(keys >= T) >= 64 ==> T is the
// 64th-largest key value. Candidates (keys >= T) are exactly the top 64
// plus any exact ties at T; exact rank (ties -> lower index, R13 formula)
// assigns unique ranks; rank < 64 writes the slot. Bit-identical output.
// No atomics in the search; 1 barrier/iter via ping-pong partial sums.
// ---------------------------------------------------------------------------
__global__ __launch_bounds__(512) void rank_kernel(
        const float* __restrict__ G,       // [NTOK, EE]
        int*   __restrict__ pick,          // [BB*EE, CAP]
        float* __restrict__ gval)          // [BB*EE, CAP]
{
    const int tid  = threadIdx.x;          // 0..511
    const int be   = blockIdx.x;           // 0..255
    const int b    = be >> 6;
    const int e    = be & 63;
    const int wave = tid >> 6;
    const int lane = tid & 63;

    __shared__ unsigned K[SS];             // 8 KB
    __shared__ int wsum[2][8];             // ping-pong partial counts
    __shared__ int cand[256];
    __shared__ int rkacc[256];
    __shared__ int scand;

    unsigned mine[4];
    #pragma unroll
    for (int j = 0; j < 4; ++j) {
        const int s = tid + 512 * j;       // covers 0..2047 exactly
        unsigned bits = __float_as_uint(G[((size_t)(b * SS + s)) * EE + e]);
        K[s] = bits;
        mine[j] = bits;
    }
    if (tid == 0) scand = 0;
    __syncthreads();

    // --- binary search the 64th-largest key value (30 iterations) ---
    unsigned T = 0;
    for (int bit = 29; bit >= 0; --bit) {
        const unsigned Tc = T | (1u << bit);
        int c = (int)(mine[0] >= Tc) + (int)(mine[1] >= Tc)
              + (int)(mine[2] >= Tc) + (int)(mine[3] >= Tc);
        #pragma unroll
        for (int off = 32; off; off >>= 1) c += __shfl_xor(c, off, 64);
        const int pp = bit & 1;
        if (lane == 0) wsum[pp][wave] = c;
        __syncthreads();                   // ping-pong: 1 barrier/iter safe
        const int tot = wsum[pp][0] + wsum[pp][1] + wsum[pp][2] + wsum[pp][3]
                      + wsum[pp][4] + wsum[pp][5] + wsum[pp][6] + wsum[pp][7];
        if (tot >= CAP) T = Tc;            // block-uniform decision
    }

    // --- compact candidates: keys >= T (top-64 + exact ties at T) ---
    #pragma unroll
    for (int j = 0; j < 4; ++j) {
        if (mine[j] >= T) {
            int idx = atomicAdd(&scand, 1);
            if (idx < 256) cand[idx] = tid + 512 * j;
        }
    }
    __syncthreads();
    const int ncand = (scand < 256) ? scand : 256;
    for (int i = tid; i < ncand; i += 512) rkacc[i] = 0;
    __syncthreads();

    // --- exact rank of candidates (R13 formula), 4 threads/candidate,
    //     interleaved strips (4i+q): 4 distinct banks, conflict-free ---
    const int quarter = tid & 3;
    for (int cid = tid >> 2; cid < ncand; cid += 128) {
        const int sc = cand[cid];
        const unsigned kc = K[sc];
        int part = 0;
        for (int i = 0; i < 512; ++i) {
            const int idx = 4 * i + quarter;
            const unsigned ki = K[idx];
            part += (int)(ki > kc) + (int)((ki == kc) && (idx < sc));
        }
        atomicAdd(&rkacc[cid], part);
    }
    __syncthreads();

    for (int cid = tid; cid < ncand; cid += 512) {
        const int r = rkacc[cid];
        if (r < CAP) {
            const int sc = cand[cid];
            pick[be * CAP + r] = sc;
            gval[be * CAP + r] = __uint_as_float(K[sc]);
        }
    }
}

// ---------------------------------------------------------------------------
// Kernel 3: streaming writer (verbatim R14). Thread g covers 4 consecutive
// capacity slots of one (b,s,e) row for BOTH tensors; perfectly coalesced
// float4 stores; pick/gval tables L2-hot.
// ---------------------------------------------------------------------------
__global__ __launch_bounds__(256) void writer_kernel(
        const int4*   __restrict__ pick4,  // [BB*EE, CAP/4]
        const float4* __restrict__ gval4,  // [BB*EE, CAP/4]
        float4* __restrict__ out)          // [2 * OUT1_ELEMS/4]
{
    const unsigned g = blockIdx.x * 256u + threadIdx.x;  // < 8,388,608
    const int c4 = g & 15;
    const int e  = (g >> 4) & 63;
    const unsigned bs = g >> 10;           // 0..8191
    const int s  = bs & 2047;
    const int b  = bs >> 11;
    const int be = b * EE + e;

    const int4   pk = pick4[be * (CAP / 4) + c4];
    const float4 gv = gval4[be * (CAP / 4) + c4];

    float4 msk, cmb;
    msk.x = (pk.x == s) ? 1.0f : 0.0f;  cmb.x = (pk.x == s) ? gv.x : 0.0f;
    msk.y = (pk.y == s) ? 1.0f : 0.0f;  cmb.y = (pk.y == s) ? gv.y : 0.0f;
    msk.z = (pk.z == s) ? 1.0f : 0.0f;  cmb.z = (pk.z == s) ? gv.z : 0.0f;
    msk.w = (pk.w == s) ? 1.0f : 0.0f;  cmb.w = (pk.w == s) ? gv.w : 0.0f;

    out[g] = msk;                          // dispatch_mask
    out[g + OUT1_ELEMS / 4] = cmb;         // combine_weights
}

// ---------------------------------------------------------------------------
extern "C" void kernel_launch(void* const* d_in, const int* in_sizes, int n_in,
                              void* d_out, int out_size, void* d_ws, size_t ws_size,
                              hipStream_t stream) {
    const float* X     = (const float*)d_in[0];   // [4,2048,1024] fp32
    const float* W     = (const float*)d_in[1];   // [1024,64]     fp32
    const float* noise = (const float*)d_in[2];   // [4,2048,64]   fp32
    float* outb = (float*)d_out;   // mask ++ combine, fp32

    // G table (2 MiB) at the combine head; compact tables in d_ws (128 KiB,
    // proven writable in R14).
    float* G    = outb + (size_t)OUT1_ELEMS;
    int*   pick = (int*)d_ws;
    float* gval = (float*)((char*)d_ws + (size_t)BB * EE * CAP * sizeof(int));

    gates_kernel<<<NTOK / 16, 256, 0, stream>>>(X, W, noise, G);
    rank_kernel<<<BB * EE, 512, 0, stream>>>(G, pick, gval);
    writer_kernel<<<OUT1_ELEMS / 4 / 256, 256, 0, stream>>>(
        (const int4*)pick, (const float4*)gval, (float4*)outb);
}